// Round 4
// baseline (450.020 us; speedup 1.0000x reference)
//
#include <hip/hip_runtime.h>
#include <math.h>

#define BB 8
#define NN 2048
#define DD 512

typedef _Float16 halfT;
typedef _Float16 half8 __attribute__((ext_vector_type(8)));
typedef _Float16 half4 __attribute__((ext_vector_type(4)));
typedef float f32x4 __attribute__((ext_vector_type(4)));

#define GLOAD16(gp, sp) __builtin_amdgcn_global_load_lds( \
    (const __attribute__((address_space(1))) void*)(gp), \
    (__attribute__((address_space(3))) void*)(sp), 16, 0, 0)

// ---------------------------------------------------------------------------
// W transpose + fp16 split:  WT[e][d] = W[d][e]  ->  (hi, lo) fp16 pairs
// ---------------------------------------------------------------------------
__global__ __launch_bounds__(256) void wsplit_kernel(
    const float* __restrict__ Wq, const float* __restrict__ Wk, const float* __restrict__ Wv,
    _Float16* __restrict__ qhT, _Float16* __restrict__ qlT,
    _Float16* __restrict__ khT, _Float16* __restrict__ klT,
    _Float16* __restrict__ vhT)
{
    __shared__ float t[64][65];
    const int z = blockIdx.z;
    const float* W = (z == 0) ? Wq : ((z == 1) ? Wk : Wv);
    _Float16* Ph = (z == 0) ? qhT : ((z == 1) ? khT : vhT);
    _Float16* Pl = (z == 0) ? qlT : ((z == 1) ? klT : nullptr);
    const int bx = blockIdx.x * 64, by = blockIdx.y * 64;
    const int tid = threadIdx.x;
    #pragma unroll
    for (int i = 0; i < 16; ++i) {
        const int idx = i * 256 + tid;
        const int r = idx >> 6, c = idx & 63;
        t[r][c] = W[(long)(by + r) * 512 + bx + c];
    }
    __syncthreads();
    #pragma unroll
    for (int i = 0; i < 16; ++i) {
        const int idx = i * 256 + tid;
        const int r = idx >> 6, c = idx & 63;
        const float v = t[c][r];
        const _Float16 h = (_Float16)v;
        const long o = (long)(bx + r) * 512 + by + c;
        Ph[o] = h;
        if (z < 2) Pl[o] = (_Float16)(v - (float)h);
    }
}

// ---------------------------------------------------------------------------
// Unified NT GEMM (m97-style) kept for projections (EPI 0,1) and AV (EPI 3).
// ---------------------------------------------------------------------------
template<int EPI>
__global__ __launch_bounds__(256) void mm_nt(
    const float* __restrict__ Af,
    const _Float16* __restrict__ Agh, const _Float16* __restrict__ Agl,
    const _Float16* __restrict__ Bgh, const _Float16* __restrict__ Bgl,
    float* __restrict__ Of, _Float16* __restrict__ Oh, _Float16* __restrict__ Ol,
    const float* __restrict__ si,
    int N, int K, long sAb, long sBb, long sOb, float scale)
{
    constexpr bool NP3    = (EPI == 0);
    constexpr bool A_FP32 = (EPI == 0 || EPI == 1);
    constexpr bool A_SPLIT = (EPI == 0);

    __shared__ __align__(16) _Float16 smem[(NP3 ? 4 : 2) * 128 * 32];
    _Float16* Ah = smem;
    _Float16* Bh = smem + 4096;
    _Float16* Al = smem + 8192;
    _Float16* Bl = smem + 12288;

    const int tid  = threadIdx.x;
    const int lane = tid & 63;
    const int w    = tid >> 6;
    const int wr   = w >> 1, wc = w & 1;
    const int z    = blockIdx.z;
    const int bm   = blockIdx.y * 128, bn = blockIdx.x * 128;

    const float* Afz = nullptr;
    const _Float16 *Aghz = nullptr, *Aglz = nullptr;
    if constexpr (A_FP32) { Afz = Af + (long)z * sAb; }
    else { Aghz = Agh + (long)z * sAb; if constexpr (NP3) Aglz = Agl + (long)z * sAb; }
    const _Float16* Bghz = Bgh + (long)z * sBb;
    const _Float16* Bglz = nullptr;
    if constexpr (NP3) Bglz = Bgl + (long)z * sBb;

    f32x4 acc[4][4];
    #pragma unroll
    for (int i = 0; i < 4; ++i)
        #pragma unroll
        for (int j = 0; j < 4; ++j) acc[i][j] = (f32x4)0.0f;

    for (int k0 = 0; k0 < K; k0 += 32) {
        #pragma unroll
        for (int i = 0; i < 2; ++i) {
            const int c   = i * 256 + w * 64 + lane;
            const int row = c >> 2, sl = c & 3;
            const long g  = (long)(bn + row) * K + k0 + sl * 8;
            const int lb  = (i * 256 + w * 64) * 8;
            GLOAD16(Bghz + g, Bh + lb);
            if constexpr (NP3) GLOAD16(Bglz + g, Bl + lb);
        }
        if constexpr (A_FP32) {
            #pragma unroll
            for (int i = 0; i < 4; ++i) {
                const int c = tid + i * 256;
                const int row = c >> 3, q4 = c & 7;
                const float4 v = *(const float4*)(Afz + (long)(bm + row) * K + k0 + q4 * 4);
                half4 h;
                h[0] = (_Float16)v.x; h[1] = (_Float16)v.y;
                h[2] = (_Float16)v.z; h[3] = (_Float16)v.w;
                *(half4*)&Ah[row * 32 + q4 * 4] = h;
                if constexpr (A_SPLIT) {
                    half4 l;
                    l[0] = (_Float16)(v.x - (float)h[0]);
                    l[1] = (_Float16)(v.y - (float)h[1]);
                    l[2] = (_Float16)(v.z - (float)h[2]);
                    l[3] = (_Float16)(v.w - (float)h[3]);
                    *(half4*)&Al[row * 32 + q4 * 4] = l;
                }
            }
        } else {
            #pragma unroll
            for (int i = 0; i < 2; ++i) {
                const int c   = i * 256 + w * 64 + lane;
                const int row = c >> 2, sl = c & 3;
                const long g  = (long)(bm + row) * K + k0 + sl * 8;
                const int lb  = (i * 256 + w * 64) * 8;
                GLOAD16(Aghz + g, Ah + lb);
            }
        }
        __syncthreads();

        half8 ah[4], bh[4], al[4], bl[4];
        #pragma unroll
        for (int f = 0; f < 4; ++f) {
            const int ar = wr * 64 + f * 16 + (lane & 15);
            const int ao = ar * 32 + ((lane >> 4) << 3);
            ah[f] = *(const half8*)&Ah[ao];
            if constexpr (NP3) al[f] = *(const half8*)&Al[ao];
            const int br = wc * 64 + f * 16 + (lane & 15);
            const int bo = br * 32 + ((lane >> 4) << 3);
            bh[f] = *(const half8*)&Bh[bo];
            if constexpr (NP3) bl[f] = *(const half8*)&Bl[bo];
        }
        #pragma unroll
        for (int i = 0; i < 4; ++i)
            #pragma unroll
            for (int j = 0; j < 4; ++j) {
                acc[i][j] = __builtin_amdgcn_mfma_f32_16x16x32_f16(ah[i], bh[j], acc[i][j], 0, 0, 0);
                if constexpr (NP3) {
                    acc[i][j] = __builtin_amdgcn_mfma_f32_16x16x32_f16(ah[i], bl[j], acc[i][j], 0, 0, 0);
                    acc[i][j] = __builtin_amdgcn_mfma_f32_16x16x32_f16(al[i], bh[j], acc[i][j], 0, 0, 0);
                }
            }
        __syncthreads();
    }

    #pragma unroll
    for (int i = 0; i < 4; ++i) {
        const int rb = bm + wr * 64 + i * 16 + ((lane >> 4) << 2);
        #pragma unroll
        for (int j = 0; j < 4; ++j) {
            const int gc = bn + wc * 64 + j * 16 + (lane & 15);
            if constexpr (EPI == 0) {
                #pragma unroll
                for (int r = 0; r < 4; ++r) {
                    const float vv = acc[i][j][r];
                    const _Float16 h = (_Float16)vv;
                    const long o = (long)(rb + r) * N + gc;
                    Oh[o] = h;
                    Ol[o] = (_Float16)(vv - (float)h);
                }
            } else if constexpr (EPI == 1) {
                half4 hv;
                #pragma unroll
                for (int r = 0; r < 4; ++r) hv[r] = (_Float16)acc[i][j][r];
                const int b = rb >> 11, rIn = rb & 2047;
                *(half4*)&Oh[((long)b * 512 + gc) * 2048 + rIn] = hv;
            } else {
                float* O = Of + (long)z * sOb;
                #pragma unroll
                for (int r = 0; r < 4; ++r)
                    O[(long)(rb + r) * N + gc] = acc[i][j][r];
            }
        }
    }
}

// ---------------------------------------------------------------------------
// scores256: 256x256 tile, 8 waves (2Mx4N, per-wave 128x64), BK=32, 3-product
// fp16-split NT GEMM. Reg-staged dbuf LDS (2x64KB) with XOR-(row&3) chunk
// swizzle => conflict-free ds_write_b128 + ds_read_b128. One raw s_barrier
// per K-step; global loads for tile t+2 fly across the whole step.
// ---------------------------------------------------------------------------
__global__ __launch_bounds__(512, 2) void scores256_kernel(
    const halfT* __restrict__ qh, const halfT* __restrict__ ql,
    const halfT* __restrict__ kh, const halfT* __restrict__ kl,
    float* __restrict__ C, const float* __restrict__ si, float scale)
{
    extern __shared__ __align__(16) char smem[];   // 131072 B: 2 sets x 64KB
    // set layout (byte offsets): Ah 0 | Al 16384 | Bh 32768 | Bl 49152

    const int tid  = threadIdx.x;
    const int lane = tid & 63;
    const int w    = tid >> 6;            // 0..7
    const int wr   = w >> 2, wc = w & 3;  // 2 x 4; per-wave out 128 x 64

    // bijective XCD swizzle of the 512-block grid
    int flat = (blockIdx.z << 6) | (blockIdx.y << 3) | blockIdx.x;
    flat = ((flat & 7) << 6) | (flat >> 3);
    const int bx = flat & 7, by = (flat >> 3) & 7, bz = flat >> 6;
    const int bm = by * 256, bn = bx * 256;

    const long zoff = (long)bz * NN * DD;
    const halfT* A_h = qh + zoff;
    const halfT* A_l = ql + zoff;
    const halfT* B_h = kh + zoff;
    const halfT* B_l = kl + zoff;

    // staging assignment: thread covers chunks c = tid and c = tid+512 of each
    // [256 rows][32 k] tile; chunk c: row=c>>2, sl=c&3 (16B = 8 halves of k)
    const int s_row0 = tid >> 2, s_sl = tid & 3;
    const int s_row1 = s_row0 + 128;
    const int s_off0 = s_row0 * 64 + ((s_sl ^ (s_row0 & 3)) << 4);
    const int s_off1 = s_row1 * 64 + ((s_sl ^ (s_row1 & 3)) << 4);
    const long gA0 = (long)(bm + s_row0) * DD + s_sl * 8;
    const long gA1 = (long)(bm + s_row1) * DD + s_sl * 8;
    const long gB0 = (long)(bn + s_row0) * DD + s_sl * 8;
    const long gB1 = (long)(bn + s_row1) * DD + s_sl * 8;

    // fragment read offset: row = base + (lane&15); row&3 == lane&3
    const int q = lane >> 4;
    const int frag_off = (lane & 15) * 64 + ((q ^ (lane & 3)) << 4);
    const int aoff = wr * 8192 + frag_off;   // + m*1024
    const int boff = wc * 4096 + frag_off;   // + n*1024

    f32x4 acc[8][4];
    #pragma unroll
    for (int m = 0; m < 8; ++m)
        #pragma unroll
        for (int n = 0; n < 4; ++n) acc[m][n] = (f32x4)0.0f;

    float4 sreg[8];
    auto load_tile = [&](int t) {
        const long kk = (long)t * 32;
        sreg[0] = *(const float4*)(A_h + gA0 + kk);
        sreg[1] = *(const float4*)(A_h + gA1 + kk);
        sreg[2] = *(const float4*)(A_l + gA0 + kk);
        sreg[3] = *(const float4*)(A_l + gA1 + kk);
        sreg[4] = *(const float4*)(B_h + gB0 + kk);
        sreg[5] = *(const float4*)(B_h + gB1 + kk);
        sreg[6] = *(const float4*)(B_l + gB0 + kk);
        sreg[7] = *(const float4*)(B_l + gB1 + kk);
    };
    auto write_tile = [&](char* setp) {
        *(float4*)(setp +     0 + s_off0) = sreg[0];
        *(float4*)(setp +     0 + s_off1) = sreg[1];
        *(float4*)(setp + 16384 + s_off0) = sreg[2];
        *(float4*)(setp + 16384 + s_off1) = sreg[3];
        *(float4*)(setp + 32768 + s_off0) = sreg[4];
        *(float4*)(setp + 32768 + s_off1) = sreg[5];
        *(float4*)(setp + 49152 + s_off0) = sreg[6];
        *(float4*)(setp + 49152 + s_off1) = sreg[7];
    };

    // prologue: tile0 -> LDS set0; tile1 -> regs
    load_tile(0);
    write_tile(smem);
    load_tile(1);
    asm volatile("s_waitcnt lgkmcnt(0)" ::: "memory");
    __builtin_amdgcn_s_barrier();
    __builtin_amdgcn_sched_barrier(0);

    for (int t = 0; t < 16; ++t) {
        char* cur = smem + (size_t)(t & 1) * 65536;
        char* nxt = smem + (size_t)((t + 1) & 1) * 65536;

        if (t < 15) write_tile(nxt);      // tile t+1 (vmcnt auto via data dep)
        if (t < 14) load_tile(t + 2);     // tile t+2, flies across this step
        __builtin_amdgcn_sched_barrier(0);

        half8 ah[8], bh[4], bl[4];
        // P1: ah x bh
        #pragma unroll
        for (int n = 0; n < 4; ++n)
            bh[n] = *(const half8*)(cur + 32768 + boff + n * 1024);
        #pragma unroll
        for (int m = 0; m < 8; ++m)
            ah[m] = *(const half8*)(cur +     0 + aoff + m * 1024);
        __builtin_amdgcn_s_setprio(1);
        #pragma unroll
        for (int m = 0; m < 8; ++m)
            #pragma unroll
            for (int n = 0; n < 4; ++n)
                acc[m][n] = __builtin_amdgcn_mfma_f32_16x16x32_f16(ah[m], bh[n], acc[m][n], 0, 0, 0);
        __builtin_amdgcn_s_setprio(0);
        // P2: ah x bl
        #pragma unroll
        for (int n = 0; n < 4; ++n)
            bl[n] = *(const half8*)(cur + 49152 + boff + n * 1024);
        __builtin_amdgcn_s_setprio(1);
        #pragma unroll
        for (int m = 0; m < 8; ++m)
            #pragma unroll
            for (int n = 0; n < 4; ++n)
                acc[m][n] = __builtin_amdgcn_mfma_f32_16x16x32_f16(ah[m], bl[n], acc[m][n], 0, 0, 0);
        __builtin_amdgcn_s_setprio(0);
        // P3: al x bh (al streamed)
        __builtin_amdgcn_s_setprio(1);
        #pragma unroll
        for (int m = 0; m < 8; ++m) {
            const half8 al = *(const half8*)(cur + 16384 + aoff + m * 1024);
            #pragma unroll
            for (int n = 0; n < 4; ++n)
                acc[m][n] = __builtin_amdgcn_mfma_f32_16x16x32_f16(al, bh[n], acc[m][n], 0, 0, 0);
        }
        __builtin_amdgcn_s_setprio(0);

        if (t < 15) {
            asm volatile("s_waitcnt lgkmcnt(0)" ::: "memory");
            __builtin_amdgcn_s_barrier();
            __builtin_amdgcn_sched_barrier(0);
        }
    }

    // epilogue: scale + diagonal bias, fp32 store
    float* Cz = C + (long)bz * NN * NN;
    #pragma unroll
    for (int m = 0; m < 8; ++m) {
        const int rb = bm + wr * 128 + m * 16 + ((lane >> 4) << 2);
        #pragma unroll
        for (int n = 0; n < 4; ++n) {
            const int gc = bn + wc * 64 + n * 16 + (lane & 15);
            #pragma unroll
            for (int r = 0; r < 4; ++r) {
                const int gr = rb + r;
                float vv = acc[m][n][r] * scale;
                if (gr == gc) vv += fminf(expf(si[gr]), 3.0f);
                Cz[(long)gr * NN + gc] = vv;
            }
        }
    }
}

// ---------------------------------------------------------------------------
// In-place row softmax + entropy partial + fp16 copy of attn.
// ---------------------------------------------------------------------------
__global__ __launch_bounds__(256) void softmax_entropy_kernel(
    float* __restrict__ attn, _Float16* __restrict__ ah, float* __restrict__ partials)
{
    __shared__ float red[4];
    const long row = blockIdx.x;
    float* p = attn + row * (long)NN;
    _Float16* ph = ah + row * (long)NN;
    const int tid = threadIdx.x;
    const int base = tid * 8;

    float4 va = *(const float4*)(p + base);
    float4 vb = *(const float4*)(p + base + 4);
    float v[8] = {va.x, va.y, va.z, va.w, vb.x, vb.y, vb.z, vb.w};

    float m = v[0];
    #pragma unroll
    for (int i = 1; i < 8; ++i) m = fmaxf(m, v[i]);
    #pragma unroll
    for (int o = 32; o; o >>= 1) m = fmaxf(m, __shfl_xor(m, o, 64));
    if ((tid & 63) == 0) red[tid >> 6] = m;
    __syncthreads();
    m = fmaxf(fmaxf(red[0], red[1]), fmaxf(red[2], red[3]));

    float t[8];
    float s = 0.f;
    #pragma unroll
    for (int i = 0; i < 8; ++i) { t[i] = v[i] - m; v[i] = expf(t[i]); s += v[i]; }
    #pragma unroll
    for (int o = 32; o; o >>= 1) s += __shfl_xor(s, o, 64);
    __syncthreads();
    if ((tid & 63) == 0) red[tid >> 6] = s;
    __syncthreads();
    s = red[0] + red[1] + red[2] + red[3];

    const float inv = 1.0f / s;
    const float lns = logf(s);
    float e = 0.f;
    float pv[8];
    #pragma unroll
    for (int i = 0; i < 8; ++i) {
        pv[i] = v[i] * inv;
        e = fmaf(pv[i], t[i] - lns, e);
    }
    *(float4*)(p + base)     = make_float4(pv[0], pv[1], pv[2], pv[3]);
    *(float4*)(p + base + 4) = make_float4(pv[4], pv[5], pv[6], pv[7]);
    half8 h;
    #pragma unroll
    for (int i = 0; i < 8; ++i) h[i] = (_Float16)pv[i];
    *(half8*)(ph + base) = h;

    #pragma unroll
    for (int o = 32; o; o >>= 1) e += __shfl_xor(e, o, 64);
    __syncthreads();
    if ((tid & 63) == 0) red[tid >> 6] = e;
    __syncthreads();
    if (tid == 0) partials[row] = red[0] + red[1] + red[2] + red[3];
}

__global__ __launch_bounds__(256) void ent_reduce_kernel(
    const float* __restrict__ partials, float* __restrict__ ent)
{
    __shared__ float red[4];
    float s = 0.f;
    for (int i = threadIdx.x; i < BB * NN; i += 256) s += partials[i];
    #pragma unroll
    for (int o = 32; o; o >>= 1) s += __shfl_xor(s, o, 64);
    if ((threadIdx.x & 63) == 0) red[threadIdx.x >> 6] = s;
    __syncthreads();
    if (threadIdx.x == 0)
        *ent = -(red[0] + red[1] + red[2] + red[3]) / (float)(BB * NN);
}

extern "C" void kernel_launch(void* const* d_in, const int* in_sizes, int n_in,
                              void* d_out, int out_size, void* d_ws, size_t ws_size,
                              hipStream_t stream) {
    const float* query = (const float*)d_in[0];
    const float* key   = (const float*)d_in[1];
    const float* value = (const float*)d_in[2];
    const float* Wq    = (const float*)d_in[3];
    const float* Wk    = (const float*)d_in[4];
    const float* Wv    = (const float*)d_in[5];
    const float* si    = (const float*)d_in[6];

    float* out  = (float*)d_out;                        // [B,N,D]
    float* attn = out + (size_t)BB * NN * DD;           // [B,N,N]
    float* ent  = attn + (size_t)BB * NN * NN;          // scalar

    const size_t NK = (size_t)BB * NN * DD;             // 8.39M elements
    _Float16* ws16 = (_Float16*)d_ws;
    _Float16* qh = ws16;            // 16.8 MB each
    _Float16* ql = qh + NK;
    _Float16* kh = ql + NK;
    _Float16* kl = kh + NK;
    _Float16* vT = kl + NK;         // vT fp16 [b][512][2048]
    _Float16* WqhT = vT + NK;       // 0.5 MB each
    _Float16* WqlT = WqhT + DD * DD;
    _Float16* WkhT = WqlT + DD * DD;
    _Float16* WklT = WkhT + DD * DD;
    _Float16* WvhT = WklT + DD * DD;
    float* partials = (float*)(WvhT + DD * DD);         // 64 KB
    _Float16* attn_h = ws16;        // 67 MB, aliases qh..kl (dead after scores)

    const dim3 blk(256);
    const float inv_sqrt_d = 0.044194173824159216f;     // 1/sqrt(512)

    wsplit_kernel<<<dim3(8, 8, 3), blk, 0, stream>>>(Wq, Wk, Wv,
        WqhT, WqlT, WkhT, WklT, WvhT);

    mm_nt<0><<<dim3(4, 128, 1), blk, 0, stream>>>(
        query, nullptr, nullptr, WqhT, WqlT, nullptr, qh, ql, nullptr,
        DD, DD, 0, 0, 0, 1.0f);
    mm_nt<0><<<dim3(4, 128, 1), blk, 0, stream>>>(
        key, nullptr, nullptr, WkhT, WklT, nullptr, kh, kl, nullptr,
        DD, DD, 0, 0, 0, 1.0f);
    mm_nt<1><<<dim3(4, 128, 1), blk, 0, stream>>>(
        value, nullptr, nullptr, WvhT, nullptr, nullptr, vT, nullptr, nullptr,
        DD, DD, 0, 0, 0, 1.0f);

    // scores = q k^T / sqrt(d) + diag(min(exp(si),3))  [new 256^2 pipeline]
    scores256_kernel<<<dim3(8, 8, 8), dim3(512), 131072, stream>>>(
        qh, ql, kh, kl, attn, si, inv_sqrt_d);

    softmax_entropy_kernel<<<dim3(BB * NN), blk, 0, stream>>>(attn, attn_h, partials);
    ent_reduce_kernel<<<dim3(1), blk, 0, stream>>>(partials, ent);

    // out = attn @ v : A = attn fp16 [2048][2048], B = vT fp16 [512][2048]
    mm_nt<3><<<dim3(4, 16, BB), blk, 0, stream>>>(
        nullptr, attn_h, nullptr, vT, nullptr, out, nullptr, nullptr, nullptr,
        DD, NN, (long)NN * NN, (long)DD * NN, (long)NN * DD, 1.0f);
}

// Round 5
// 336.485 us; speedup vs baseline: 1.3374x; 1.3374x over previous
//
#include <hip/hip_runtime.h>
#include <math.h>

#define BB 8
#define NN 2048
#define DD 512

typedef _Float16 halfT;
typedef _Float16 half8 __attribute__((ext_vector_type(8)));
typedef _Float16 half4 __attribute__((ext_vector_type(4)));
typedef float f32x4 __attribute__((ext_vector_type(4)));

#define GLOAD16(gp, sp) __builtin_amdgcn_global_load_lds( \
    (const __attribute__((address_space(1))) void*)(gp), \
    (__attribute__((address_space(3))) void*)(sp), 16, 0, 0)

// ---------------------------------------------------------------------------
// W transpose + fp16 split:  WT[e][d] = W[d][e]  ->  (hi, lo) fp16 pairs
// ---------------------------------------------------------------------------
__global__ __launch_bounds__(256) void wsplit_kernel(
    const float* __restrict__ Wq, const float* __restrict__ Wk, const float* __restrict__ Wv,
    _Float16* __restrict__ qhT, _Float16* __restrict__ qlT,
    _Float16* __restrict__ khT, _Float16* __restrict__ klT,
    _Float16* __restrict__ vhT)
{
    __shared__ float t[64][65];
    const int z = blockIdx.z;
    const float* W = (z == 0) ? Wq : ((z == 1) ? Wk : Wv);
    _Float16* Ph = (z == 0) ? qhT : ((z == 1) ? khT : vhT);
    _Float16* Pl = (z == 0) ? qlT : ((z == 1) ? klT : nullptr);
    const int bx = blockIdx.x * 64, by = blockIdx.y * 64;
    const int tid = threadIdx.x;
    #pragma unroll
    for (int i = 0; i < 16; ++i) {
        const int idx = i * 256 + tid;
        const int r = idx >> 6, c = idx & 63;
        t[r][c] = W[(long)(by + r) * 512 + bx + c];
    }
    __syncthreads();
    #pragma unroll
    for (int i = 0; i < 16; ++i) {
        const int idx = i * 256 + tid;
        const int r = idx >> 6, c = idx & 63;
        const float v = t[c][r];
        const _Float16 h = (_Float16)v;
        const long o = (long)(bx + r) * 512 + by + c;
        Ph[o] = h;
        if (z < 2) Pl[o] = (_Float16)(v - (float)h);
    }
}

// ---------------------------------------------------------------------------
// Unified NT GEMM (m97-style) kept for projections (EPI 0,1) and AV (EPI 3).
// ---------------------------------------------------------------------------
template<int EPI>
__global__ __launch_bounds__(256) void mm_nt(
    const float* __restrict__ Af,
    const _Float16* __restrict__ Agh, const _Float16* __restrict__ Agl,
    const _Float16* __restrict__ Bgh, const _Float16* __restrict__ Bgl,
    float* __restrict__ Of, _Float16* __restrict__ Oh, _Float16* __restrict__ Ol,
    const float* __restrict__ si,
    int N, int K, long sAb, long sBb, long sOb, float scale)
{
    constexpr bool NP3    = (EPI == 0);
    constexpr bool A_FP32 = (EPI == 0 || EPI == 1);
    constexpr bool A_SPLIT = (EPI == 0);

    __shared__ __align__(16) _Float16 smem[(NP3 ? 4 : 2) * 128 * 32];
    _Float16* Ah = smem;
    _Float16* Bh = smem + 4096;
    _Float16* Al = smem + 8192;
    _Float16* Bl = smem + 12288;

    const int tid  = threadIdx.x;
    const int lane = tid & 63;
    const int w    = tid >> 6;
    const int wr   = w >> 1, wc = w & 1;
    const int z    = blockIdx.z;
    const int bm   = blockIdx.y * 128, bn = blockIdx.x * 128;

    const float* Afz = nullptr;
    const _Float16 *Aghz = nullptr, *Aglz = nullptr;
    if constexpr (A_FP32) { Afz = Af + (long)z * sAb; }
    else { Aghz = Agh + (long)z * sAb; if constexpr (NP3) Aglz = Agl + (long)z * sAb; }
    const _Float16* Bghz = Bgh + (long)z * sBb;
    const _Float16* Bglz = nullptr;
    if constexpr (NP3) Bglz = Bgl + (long)z * sBb;

    f32x4 acc[4][4];
    #pragma unroll
    for (int i = 0; i < 4; ++i)
        #pragma unroll
        for (int j = 0; j < 4; ++j) acc[i][j] = (f32x4)0.0f;

    for (int k0 = 0; k0 < K; k0 += 32) {
        #pragma unroll
        for (int i = 0; i < 2; ++i) {
            const int c   = i * 256 + w * 64 + lane;
            const int row = c >> 2, sl = c & 3;
            const long g  = (long)(bn + row) * K + k0 + sl * 8;
            const int lb  = (i * 256 + w * 64) * 8;
            GLOAD16(Bghz + g, Bh + lb);
            if constexpr (NP3) GLOAD16(Bglz + g, Bl + lb);
        }
        if constexpr (A_FP32) {
            #pragma unroll
            for (int i = 0; i < 4; ++i) {
                const int c = tid + i * 256;
                const int row = c >> 3, q4 = c & 7;
                const float4 v = *(const float4*)(Afz + (long)(bm + row) * K + k0 + q4 * 4);
                half4 h;
                h[0] = (_Float16)v.x; h[1] = (_Float16)v.y;
                h[2] = (_Float16)v.z; h[3] = (_Float16)v.w;
                *(half4*)&Ah[row * 32 + q4 * 4] = h;
                if constexpr (A_SPLIT) {
                    half4 l;
                    l[0] = (_Float16)(v.x - (float)h[0]);
                    l[1] = (_Float16)(v.y - (float)h[1]);
                    l[2] = (_Float16)(v.z - (float)h[2]);
                    l[3] = (_Float16)(v.w - (float)h[3]);
                    *(half4*)&Al[row * 32 + q4 * 4] = l;
                }
            }
        } else {
            #pragma unroll
            for (int i = 0; i < 2; ++i) {
                const int c   = i * 256 + w * 64 + lane;
                const int row = c >> 2, sl = c & 3;
                const long g  = (long)(bm + row) * K + k0 + sl * 8;
                const int lb  = (i * 256 + w * 64) * 8;
                GLOAD16(Aghz + g, Ah + lb);
            }
        }
        __syncthreads();

        half8 ah[4], bh[4], al[4], bl[4];
        #pragma unroll
        for (int f = 0; f < 4; ++f) {
            const int ar = wr * 64 + f * 16 + (lane & 15);
            const int ao = ar * 32 + ((lane >> 4) << 3);
            ah[f] = *(const half8*)&Ah[ao];
            if constexpr (NP3) al[f] = *(const half8*)&Al[ao];
            const int br = wc * 64 + f * 16 + (lane & 15);
            const int bo = br * 32 + ((lane >> 4) << 3);
            bh[f] = *(const half8*)&Bh[bo];
            if constexpr (NP3) bl[f] = *(const half8*)&Bl[bo];
        }
        #pragma unroll
        for (int i = 0; i < 4; ++i)
            #pragma unroll
            for (int j = 0; j < 4; ++j) {
                acc[i][j] = __builtin_amdgcn_mfma_f32_16x16x32_f16(ah[i], bh[j], acc[i][j], 0, 0, 0);
                if constexpr (NP3) {
                    acc[i][j] = __builtin_amdgcn_mfma_f32_16x16x32_f16(ah[i], bl[j], acc[i][j], 0, 0, 0);
                    acc[i][j] = __builtin_amdgcn_mfma_f32_16x16x32_f16(al[i], bh[j], acc[i][j], 0, 0, 0);
                }
            }
        __syncthreads();
    }

    #pragma unroll
    for (int i = 0; i < 4; ++i) {
        const int rb = bm + wr * 64 + i * 16 + ((lane >> 4) << 2);
        #pragma unroll
        for (int j = 0; j < 4; ++j) {
            const int gc = bn + wc * 64 + j * 16 + (lane & 15);
            if constexpr (EPI == 0) {
                #pragma unroll
                for (int r = 0; r < 4; ++r) {
                    const float vv = acc[i][j][r];
                    const _Float16 h = (_Float16)vv;
                    const long o = (long)(rb + r) * N + gc;
                    Oh[o] = h;
                    Ol[o] = (_Float16)(vv - (float)h);
                }
            } else if constexpr (EPI == 1) {
                half4 hv;
                #pragma unroll
                for (int r = 0; r < 4; ++r) hv[r] = (_Float16)acc[i][j][r];
                const int b = rb >> 11, rIn = rb & 2047;
                *(half4*)&Oh[((long)b * 512 + gc) * 2048 + rIn] = hv;
            } else {
                float* O = Of + (long)z * sOb;
                #pragma unroll
                for (int r = 0; r < 4; ++r)
                    O[(long)(rb + r) * N + gc] = acc[i][j][r];
            }
        }
    }
}

// ---------------------------------------------------------------------------
// scores256 v2: 256x256 tile, 8 waves (2Mx4N, per-wave 128x64), BK=32,
// 3-product fp16-split NT GEMM.
//   - global_load_lds staging (NO staging registers -> no spill)
//   - LDS linear dest + PRE-SWIZZLED global source; read side applies the
//     same involution  chunk_phys = chunk ^ ((row>>1)&3)  => every 16-lane
//     b128 access covers all 8 16B-granules exactly twice (conflict-free).
//   - 2-phase schedule: issue next tile's 8 gload_lds BEFORE compute, one
//     vmcnt(0) + raw s_barrier per K-step (loads fly across the MFMA block).
// ---------------------------------------------------------------------------
__global__ __launch_bounds__(512, 2) void scores256_kernel(
    const halfT* __restrict__ qh, const halfT* __restrict__ ql,
    const halfT* __restrict__ kh, const halfT* __restrict__ kl,
    float* __restrict__ C, const float* __restrict__ si, float scale)
{
    extern __shared__ __align__(16) char smem[];   // 2 x 65536 B
    // buffer layout (byte offsets): Ah 0 | Al 16384 | Bh 32768 | Bl 49152

    const int tid  = threadIdx.x;
    const int lane = tid & 63;
    const int w    = tid >> 6;            // 0..7
    const int wr   = w >> 2, wc = w & 3;  // per-wave output 128 x 64

    // bijective XCD swizzle of the 512-block grid
    int flat = (blockIdx.z << 6) | (blockIdx.y << 3) | blockIdx.x;
    flat = ((flat & 7) << 6) | (flat >> 3);
    const int bx = flat & 7, by = (flat >> 3) & 7, bz = flat >> 6;
    const int bm = by * 256, bn = bx * 256;

    const long zoff = (long)bz * NN * DD;
    const halfT* A_h = qh + zoff;
    const halfT* A_l = ql + zoff;
    const halfT* B_h = kh + zoff;
    const halfT* B_l = kl + zoff;

    // staging: pass i (0/1) covers rows i*128 + w*16 + (lane>>2);
    // lane loads global k-chunk  (lane&3) ^ ((lane>>3)&3)  [pre-swizzle]
    const int s_row   = w * 16 + (lane >> 2);
    const int s_chunk = (lane & 3) ^ ((lane >> 3) & 3);
    const long gA = (long)(bm + s_row) * DD + s_chunk * 8;
    const long gB = (long)(bn + s_row) * DD + s_chunk * 8;

    auto stage = [&](char* buf, int t) {
        const long kk = (long)t * 32;
        #pragma unroll
        for (int i = 0; i < 2; ++i) {
            const long ra = gA + (long)i * 128 * DD + kk;
            const long rb = gB + (long)i * 128 * DD + kk;
            char* d = buf + i * 8192 + w * 1024;       // wave-uniform base
            GLOAD16(A_h + ra, d);
            GLOAD16(A_l + ra, d + 16384);
            GLOAD16(B_h + rb, d + 32768);
            GLOAD16(B_l + rb, d + 49152);
        }
    };

    // fragment read offset (same involution on the read side)
    const int lr   = lane & 15;
    const int q16  = lane >> 4;
    const int fswz = (lr >> 1) & 3;
    const int frag = lr * 64 + ((q16 ^ fswz) << 4);
    const int abase = wr * 8192 + frag;     // + m*1024
    const int bbase = wc * 4096 + frag;     // + n*1024

    f32x4 acc[8][4];
    #pragma unroll
    for (int m = 0; m < 8; ++m)
        #pragma unroll
        for (int n = 0; n < 4; ++n) acc[m][n] = (f32x4)0.0f;

    // prologue
    stage(smem, 0);
    asm volatile("s_waitcnt vmcnt(0)" ::: "memory");
    __builtin_amdgcn_s_barrier();

    for (int t = 0; t < 16; ++t) {
        char* cur = smem + (size_t)(t & 1) * 65536;
        char* nxt = smem + (size_t)((t + 1) & 1) * 65536;

        if (t < 15) stage(nxt, t + 1);   // 8 gload_lds fly across this step

        half8 ah[8], bh[4], bl[4];
        #pragma unroll
        for (int n = 0; n < 4; ++n)
            bh[n] = *(const half8*)(cur + 32768 + bbase + n * 1024);
        #pragma unroll
        for (int m = 0; m < 8; ++m)
            ah[m] = *(const half8*)(cur + abase + m * 1024);
        __builtin_amdgcn_s_setprio(1);
        #pragma unroll
        for (int m = 0; m < 8; ++m)
            #pragma unroll
            for (int n = 0; n < 4; ++n)
                acc[m][n] = __builtin_amdgcn_mfma_f32_16x16x32_f16(ah[m], bh[n], acc[m][n], 0, 0, 0);
        __builtin_amdgcn_s_setprio(0);

        #pragma unroll
        for (int n = 0; n < 4; ++n)
            bl[n] = *(const half8*)(cur + 49152 + bbase + n * 1024);
        __builtin_amdgcn_s_setprio(1);
        #pragma unroll
        for (int m = 0; m < 8; ++m)
            #pragma unroll
            for (int n = 0; n < 4; ++n)
                acc[m][n] = __builtin_amdgcn_mfma_f32_16x16x32_f16(ah[m], bl[n], acc[m][n], 0, 0, 0);
        __builtin_amdgcn_s_setprio(0);

        __builtin_amdgcn_s_setprio(1);
        #pragma unroll
        for (int m = 0; m < 8; ++m) {
            const half8 al = *(const half8*)(cur + 16384 + abase + m * 1024);
            #pragma unroll
            for (int n = 0; n < 4; ++n)
                acc[m][n] = __builtin_amdgcn_mfma_f32_16x16x32_f16(al, bh[n], acc[m][n], 0, 0, 0);
        }
        __builtin_amdgcn_s_setprio(0);

        if (t < 15) {
            asm volatile("s_waitcnt vmcnt(0)" ::: "memory");
            __builtin_amdgcn_s_barrier();
        }
    }

    // epilogue: scale + diagonal bias, fp32 store
    float* Cz = C + (long)bz * NN * NN;
    #pragma unroll
    for (int m = 0; m < 8; ++m) {
        const int rb = bm + wr * 128 + m * 16 + ((lane >> 4) << 2);
        #pragma unroll
        for (int n = 0; n < 4; ++n) {
            const int gc = bn + wc * 64 + n * 16 + (lane & 15);
            #pragma unroll
            for (int r = 0; r < 4; ++r) {
                const int gr = rb + r;
                float vv = acc[m][n][r] * scale;
                if (gr == gc) vv += fminf(expf(si[gr]), 3.0f);
                Cz[(long)gr * NN + gc] = vv;
            }
        }
    }
}

// ---------------------------------------------------------------------------
// In-place row softmax + entropy partial + fp16 copy of attn.
// ---------------------------------------------------------------------------
__global__ __launch_bounds__(256) void softmax_entropy_kernel(
    float* __restrict__ attn, _Float16* __restrict__ ah, float* __restrict__ partials)
{
    __shared__ float red[4];
    const long row = blockIdx.x;
    float* p = attn + row * (long)NN;
    _Float16* ph = ah + row * (long)NN;
    const int tid = threadIdx.x;
    const int base = tid * 8;

    float4 va = *(const float4*)(p + base);
    float4 vb = *(const float4*)(p + base + 4);
    float v[8] = {va.x, va.y, va.z, va.w, vb.x, vb.y, vb.z, vb.w};

    float m = v[0];
    #pragma unroll
    for (int i = 1; i < 8; ++i) m = fmaxf(m, v[i]);
    #pragma unroll
    for (int o = 32; o; o >>= 1) m = fmaxf(m, __shfl_xor(m, o, 64));
    if ((tid & 63) == 0) red[tid >> 6] = m;
    __syncthreads();
    m = fmaxf(fmaxf(red[0], red[1]), fmaxf(red[2], red[3]));

    float t[8];
    float s = 0.f;
    #pragma unroll
    for (int i = 0; i < 8; ++i) { t[i] = v[i] - m; v[i] = expf(t[i]); s += v[i]; }
    #pragma unroll
    for (int o = 32; o; o >>= 1) s += __shfl_xor(s, o, 64);
    __syncthreads();
    if ((tid & 63) == 0) red[tid >> 6] = s;
    __syncthreads();
    s = red[0] + red[1] + red[2] + red[3];

    const float inv = 1.0f / s;
    const float lns = logf(s);
    float e = 0.f;
    float pv[8];
    #pragma unroll
    for (int i = 0; i < 8; ++i) {
        pv[i] = v[i] * inv;
        e = fmaf(pv[i], t[i] - lns, e);
    }
    *(float4*)(p + base)     = make_float4(pv[0], pv[1], pv[2], pv[3]);
    *(float4*)(p + base + 4) = make_float4(pv[4], pv[5], pv[6], pv[7]);
    half8 h;
    #pragma unroll
    for (int i = 0; i < 8; ++i) h[i] = (_Float16)pv[i];
    *(half8*)(ph + base) = h;

    #pragma unroll
    for (int o = 32; o; o >>= 1) e += __shfl_xor(e, o, 64);
    __syncthreads();
    if ((tid & 63) == 0) red[tid >> 6] = e;
    __syncthreads();
    if (tid == 0) partials[row] = red[0] + red[1] + red[2] + red[3];
}

__global__ __launch_bounds__(256) void ent_reduce_kernel(
    const float* __restrict__ partials, float* __restrict__ ent)
{
    __shared__ float red[4];
    float s = 0.f;
    for (int i = threadIdx.x; i < BB * NN; i += 256) s += partials[i];
    #pragma unroll
    for (int o = 32; o; o >>= 1) s += __shfl_xor(s, o, 64);
    if ((threadIdx.x & 63) == 0) red[threadIdx.x >> 6] = s;
    __syncthreads();
    if (threadIdx.x == 0)
        *ent = -(red[0] + red[1] + red[2] + red[3]) / (float)(BB * NN);
}

extern "C" void kernel_launch(void* const* d_in, const int* in_sizes, int n_in,
                              void* d_out, int out_size, void* d_ws, size_t ws_size,
                              hipStream_t stream) {
    const float* query = (const float*)d_in[0];
    const float* key   = (const float*)d_in[1];
    const float* value = (const float*)d_in[2];
    const float* Wq    = (const float*)d_in[3];
    const float* Wk    = (const float*)d_in[4];
    const float* Wv    = (const float*)d_in[5];
    const float* si    = (const float*)d_in[6];

    float* out  = (float*)d_out;                        // [B,N,D]
    float* attn = out + (size_t)BB * NN * DD;           // [B,N,N]
    float* ent  = attn + (size_t)BB * NN * NN;          // scalar

    const size_t NK = (size_t)BB * NN * DD;             // 8.39M elements
    _Float16* ws16 = (_Float16*)d_ws;
    _Float16* qh = ws16;            // 16.8 MB each
    _Float16* ql = qh + NK;
    _Float16* kh = ql + NK;
    _Float16* kl = kh + NK;
    _Float16* vT = kl + NK;         // vT fp16 [b][512][2048]
    _Float16* WqhT = vT + NK;       // 0.5 MB each
    _Float16* WqlT = WqhT + DD * DD;
    _Float16* WkhT = WqlT + DD * DD;
    _Float16* WklT = WkhT + DD * DD;
    _Float16* WvhT = WklT + DD * DD;
    float* partials = (float*)(WvhT + DD * DD);         // 64 KB
    _Float16* attn_h = ws16;        // 67 MB, aliases qh..kl (dead after scores)

    const dim3 blk(256);
    const float inv_sqrt_d = 0.044194173824159216f;     // 1/sqrt(512)

    wsplit_kernel<<<dim3(8, 8, 3), blk, 0, stream>>>(Wq, Wk, Wv,
        WqhT, WqlT, WkhT, WklT, WvhT);

    mm_nt<0><<<dim3(4, 128, 1), blk, 0, stream>>>(
        query, nullptr, nullptr, WqhT, WqlT, nullptr, qh, ql, nullptr,
        DD, DD, 0, 0, 0, 1.0f);
    mm_nt<0><<<dim3(4, 128, 1), blk, 0, stream>>>(
        key, nullptr, nullptr, WkhT, WklT, nullptr, kh, kl, nullptr,
        DD, DD, 0, 0, 0, 1.0f);
    mm_nt<1><<<dim3(4, 128, 1), blk, 0, stream>>>(
        value, nullptr, nullptr, WvhT, nullptr, nullptr, vT, nullptr, nullptr,
        DD, DD, 0, 0, 0, 1.0f);

    // scores = q k^T / sqrt(d) + diag(min(exp(si),3))  [256^2 v2 pipeline]
    scores256_kernel<<<dim3(8, 8, 8), dim3(512), 131072, stream>>>(
        qh, ql, kh, kl, attn, si, inv_sqrt_d);

    softmax_entropy_kernel<<<dim3(BB * NN), blk, 0, stream>>>(attn, attn_h, partials);
    ent_reduce_kernel<<<dim3(1), blk, 0, stream>>>(partials, ent);

    // out = attn @ v : A = attn fp16 [2048][2048], B = vT fp16 [512][2048]
    mm_nt<3><<<dim3(4, 16, BB), blk, 0, stream>>>(
        nullptr, attn_h, nullptr, vT, nullptr, out, nullptr, nullptr, nullptr,
        DD, NN, (long)NN * NN, (long)DD * NN, (long)NN * DD, 1.0f);
}